// Round 4
// baseline (77.738 us; speedup 1.0000x reference)
//
#include <hip/hip_runtime.h>
#include <math.h>

// Problem constants (fixed by setup_inputs): bs=16, Q=300, C=2, P=320
#define BS 16
#define QN 300
#define CN 2
#define PN 320
#define NN (BS * QN)   // 4800 query rows
#define KPRED 53
#define KTGT 54
#define TILE_N 4       // query rows per block -> 1200 blocks
#define STAGE_N (TILE_N * KPRED + TILE_N * CN)   // 220 staged floats

// ws layout: T[72][320] fp32 transposed target features (92160 B)
//   rows  0..17 : tx_j      = tgt[p][3j]
//   rows 18..35 : ty_j      = tgt[p][3j+1]
//   rows 36..53 : w_j (raw) = tgt[p][3j+2]   (vis slot / kpts-class target)
//   rows 54..71 : vjf_j     = (w_j == 1.0f) ? 1 : 0
#define TROW_TX  0
#define TROW_TY  18
#define TROW_W   36
#define TROW_V   54

// Prologue: transpose + precompute vis. 5 blocks x 64 threads, ~1 us.
// Reads are uncoalesced ONCE (69 KB total); writes fully coalesced.
__global__ __launch_bounds__(64) void tgt_transpose_kernel(
    const float* __restrict__ tgt_kpts,   // [320, 54]
    float* __restrict__ T)                // [72, 320]
{
    const int p = blockIdx.x * 64 + threadIdx.x;   // 0..319
    const float* t = tgt_kpts + (size_t)p * KTGT;
    #pragma unroll
    for (int j = 0; j < 18; ++j) {
        const float a = t[3 * j];
        const float b = t[3 * j + 1];
        const float c = t[3 * j + 2];
        T[(TROW_TX + j) * PN + p] = a;
        T[(TROW_TY + j) * PN + p] = b;
        T[(TROW_W  + j) * PN + p] = c;
        T[(TROW_V  + j) * PN + p] = (c == 1.0f) ? 1.0f : 0.0f;
    }
}

// Main: thread = target p (0..319, 5 waves/block); block handles TILE_N rows.
// Target features now load via 72 fully-coalesced dword loads from T
// (lane p <-> column p) instead of 54 floats at 216 B lane stride — kills the
// 64-lines-per-instruction L1 divergence that dominated rounds 1-3.
__global__ __launch_bounds__(PN) void hungarian_cost_kernel(
    const float* __restrict__ pred_logits,  // [N, 2]
    const float* __restrict__ pred_kpts,    // [N, 53]
    const float* __restrict__ T,            // [72, 320] transposed targets
    const int*   __restrict__ tgt_ids,      // [P]
    float* __restrict__ out)                // [N, P]
{
    __shared__ float sk[STAGE_N];
    const int p  = threadIdx.x;
    const int n0 = blockIdx.x * TILE_N;

    // ---- coalesced staging of pred rows: 212 kpts floats + 8 logits ----
    if (p < STAGE_N) {
        sk[p] = (p < TILE_N * KPRED)
                    ? pred_kpts[(size_t)n0 * KPRED + p]
                    : pred_logits[n0 * CN + (p - TILE_N * KPRED)];
    }

    // ---- coalesced per-thread target features ----
    float tx[18], ty[18], vjf[18], w[17];
    #pragma unroll
    for (int j = 0; j < 18; ++j) {
        tx[j]  = T[(TROW_TX + j) * PN + p];
        ty[j]  = T[(TROW_TY + j) * PN + p];
        vjf[j] = T[(TROW_V  + j) * PN + p];
    }
    #pragma unroll
    for (int j = 1; j < 18; ++j) w[j - 1] = T[(TROW_W + j) * PN + p];
    const int cls = tgt_ids[p];

    __syncthreads();

    #pragma unroll
    for (int ni = 0; ni < TILE_N; ++ni) {
        const int n = n0 + ni;
        const float* k = &sk[ni * KPRED];   // broadcast LDS reads

        const float dx0 = k[0] - tx[0];
        const float dy0 = k[1] - ty[0];

        float cd = 0.0f;   // cost_deltas (L1, relative coords)
        float ck = 0.0f;   // cost_kpts:  xa - txa = 2*dx + dx0
        float cq = 0.0f;   // kpts-class squared L2
        #pragma unroll
        for (int j = 1; j < 18; ++j) {
            const float dx = k[3 * j - 1] - tx[j];
            const float dy = k[3 * j]     - ty[j];
            cd = fmaf(vjf[j], fabsf(dx) + fabsf(dy), cd);
            const float ax = fmaf(2.0f, dx, dx0);
            const float ay = fmaf(2.0f, dy, dy0);
            ck = fmaf(vjf[j], fabsf(ax) + fabsf(ay), ck);
            const float d = k[3 * j + 1] - w[j - 1];
            cq = fmaf(d, d, cq);
        }

        // cost_ctrs = vis0 * ||(dx0, dy0)||
        const float cc = vjf[0] * sqrtf(fmaf(dx0, dx0, dy0 * dy0));

        // cost_class = -softmax(logits)[cls]
        const float l0 = sk[TILE_N * KPRED + 2 * ni];
        const float l1 = sk[TILE_N * KPRED + 2 * ni + 1];
        const float m  = fmaxf(l0, l1);
        const float e0 = __expf(l0 - m);
        const float e1 = __expf(l1 - m);
        const float inv = 1.0f / (e0 + e1);
        const float ccls = -((cls == 0) ? e0 : e1) * inv;

        out[(size_t)n * PN + p] = ck + cc + cd + ccls + sqrtf(cq);
    }
}

extern "C" void kernel_launch(void* const* d_in, const int* in_sizes, int n_in,
                              void* d_out, int out_size, void* d_ws, size_t ws_size,
                              hipStream_t stream) {
    const float* pred_logits = (const float*)d_in[0];
    const float* pred_kpts   = (const float*)d_in[1];
    const float* tgt_kpts    = (const float*)d_in[2];
    const int*   tgt_ids     = (const int*)d_in[3];
    float* out = (float*)d_out;
    float* T   = (float*)d_ws;   // 72*320 floats = 92160 B

    hipLaunchKernelGGL(tgt_transpose_kernel, dim3(PN / 64), dim3(64), 0, stream,
                       tgt_kpts, T);
    hipLaunchKernelGGL(hungarian_cost_kernel, dim3(NN / TILE_N), dim3(PN), 0, stream,
                       pred_logits, pred_kpts, T, tgt_ids, out);
}

// Round 5
// 77.489 us; speedup vs baseline: 1.0032x; 1.0032x over previous
//
#include <hip/hip_runtime.h>
#include <math.h>

// Problem constants (fixed by setup_inputs): bs=16, Q=300, C=2, P=320
#define BS 16
#define QN 300
#define CN 2
#define PN 320
#define NN (BS * QN)   // 4800 query rows
#define KPRED 53
#define KTGT 54

#define NTILE 64       // query rows per block (lane <-> row)
#define PCH 32         // targets per block -> grid (75, 10)
#define NWAVES 4       // 256 threads
#define PPW (PCH / NWAVES)   // 8 targets per wave
#define TPAD 36        // out-tile row stride in words (64x32 tile, padded)

// Inverted decomposition: lane <-> query row, wave loops over targets.
// Pred features load ONCE per wave into registers (no per-lane loads in the
// inner loop). Target row address is wave-uniform (readfirstlane'd wave id)
// so the 54 target floats come in as s_loads on the scalar pipe — no VALU,
// no VGPR cost, prefetchable. Inner loop is pure VALU (~255 ops per target).
// Results staged via padded LDS tile so global stores stay coalesced [N,P].
__global__ __launch_bounds__(256) void hungarian_cost_kernel(
    const float* __restrict__ pred_logits,  // [N, 2]
    const float* __restrict__ pred_kpts,    // [N, 53]
    const float* __restrict__ tgt_kpts,     // [P, 54]
    const int*   __restrict__ tgt_ids,      // [P]
    float* __restrict__ out)                // [N, P]
{
    __shared__ float sk[NTILE * KPRED];   // staged pred kpt rows (13.2 KB)
    __shared__ float sl[NTILE * CN];      // staged logits
    __shared__ float tile[NTILE * TPAD];  // 64x32 out tile, pad->36 (9.2 KB)

    const int tid  = threadIdx.x;
    const int lane = tid & 63;
    const int wid  = __builtin_amdgcn_readfirstlane(tid >> 6);  // wave-uniform
    const int n0 = blockIdx.x * NTILE;
    const int p0 = blockIdx.y * PCH;

    // ---- coalesced staging of 64 pred rows + logits ----
    for (int i = tid; i < NTILE * KPRED; i += 256)
        sk[i] = pred_kpts[(size_t)n0 * KPRED + i];
    for (int i = tid; i < NTILE * CN; i += 256)
        sl[i] = pred_logits[(size_t)n0 * CN + i];
    __syncthreads();

    // ---- per-lane pred features -> registers (row stride 53 words: odd ->
    //      2 lanes/bank, conflict-free) ----
    float x[18], y[18], kc[17];
    {
        const float* k = &sk[lane * KPRED];
        x[0] = k[0]; y[0] = k[1];
        #pragma unroll
        for (int j = 1; j < 18; ++j) {
            x[j] = k[3 * j - 1];
            y[j] = k[3 * j];
            kc[j - 1] = k[3 * j + 1];
        }
    }
    const float l0 = sl[lane * 2], l1 = sl[lane * 2 + 1];
    const float mm = fmaxf(l0, l1);
    const float e0 = __expf(l0 - mm), e1 = __expf(l1 - mm);
    const float inv = 1.0f / (e0 + e1);
    const float pr0 = e0 * inv, pr1 = e1 * inv;

    // ---- wave-loop over this wave's 8 targets (uniform p -> s_loads) ----
    #pragma unroll 2
    for (int it = 0; it < PPW; ++it) {
        const int pc = wid * PPW + it;   // tile column, wave-uniform
        const int p  = p0 + pc;
        const float* t = tgt_kpts + (size_t)p * KTGT;   // uniform address
        const int cls = tgt_ids[p];

        const float tx0 = t[0], ty0 = t[1];
        const float v0  = (t[2] == 1.0f) ? 1.0f : 0.0f;   // scalar-side
        const float dx0 = x[0] - tx0;
        const float dy0 = y[0] - ty0;

        float cd = 0.0f, ck = 0.0f, cq = 0.0f;
        #pragma unroll
        for (int j = 1; j < 18; ++j) {
            const float txj = t[3 * j], tyj = t[3 * j + 1], wj = t[3 * j + 2];
            const float vj  = (wj == 1.0f) ? 1.0f : 0.0f;  // scalar-side
            const float dx = x[j] - txj;
            const float dy = y[j] - tyj;
            cd = fmaf(vj, fabsf(dx) + fabsf(dy), cd);
            const float ax = fmaf(2.0f, dx, dx0);
            const float ay = fmaf(2.0f, dy, dy0);
            ck = fmaf(vj, fabsf(ax) + fabsf(ay), ck);
            const float d = kc[j - 1] - wj;
            cq = fmaf(d, d, cq);
        }

        const float cc   = v0 * sqrtf(fmaf(dx0, dx0, dy0 * dy0));
        const float ccls = -((cls == 0) ? pr0 : pr1);

        // column write: lane stride 36 words (8-way bank alias, 1 instr/iter)
        tile[lane * TPAD + pc] = ck + cc + cd + ccls + sqrtf(cq);
    }
    __syncthreads();

    // ---- coalesced flush: thread t -> row t/4, cols (t&3)*8 .. +7 ----
    {
        const int r  = tid >> 2;
        const int c0 = (tid & 3) * 8;
        const float* src = &tile[r * TPAD + c0];
        float* dst = &out[(size_t)(n0 + r) * PN + p0 + c0];
        #pragma unroll
        for (int i = 0; i < 8; ++i) dst[i] = src[i];
    }
}

extern "C" void kernel_launch(void* const* d_in, const int* in_sizes, int n_in,
                              void* d_out, int out_size, void* d_ws, size_t ws_size,
                              hipStream_t stream) {
    const float* pred_logits = (const float*)d_in[0];
    const float* pred_kpts   = (const float*)d_in[1];
    const float* tgt_kpts    = (const float*)d_in[2];
    const int*   tgt_ids     = (const int*)d_in[3];
    float* out = (float*)d_out;

    dim3 grid(NN / NTILE, PN / PCH);   // (75, 10) = 750 blocks
    dim3 block(NWAVES * 64);           // 256 threads
    hipLaunchKernelGGL(hungarian_cost_kernel, grid, block, 0, stream,
                       pred_logits, pred_kpts, tgt_kpts, tgt_ids, out);
}